// Round 2
// baseline (1281.549 us; speedup 1.0000x reference)
//
#include <hip/hip_runtime.h>

namespace {

constexpr int kB = 4096;
constexpr int kT = 2048;
constexpr int kH = 32;
constexpr int kHalf = 16;          // split-K half
constexpr int kWavesPerBlock = 4;  // 256 threads

typedef float4 f4a __attribute__((may_alias));

__device__ __forceinline__ float fast_tanh(float x) {
  // tanh(x) = 1 - 2/(exp(2x)+1); exp via exp2, ~1ulp each
  float e = __builtin_amdgcn_exp2f(x * 2.885390081777926815f); // 2*log2(e)
  float r = __builtin_amdgcn_rcpf(e + 1.0f);
  return fmaf(-2.0f, r, 1.0f);
}

template <int CTRL>
__device__ __forceinline__ float dpp_add(float x) {
  int xi = __builtin_bit_cast(int, x);
  int ri = __builtin_amdgcn_update_dpp(0, xi, CTRL, 0xF, 0xF, true);
  return x + __builtin_bit_cast(float, ri);
}

__device__ __forceinline__ float readlane_f(float v, int l) {
  return __builtin_bit_cast(
      float, __builtin_amdgcn_readlane(__builtin_bit_cast(int, v), l));
}

__device__ __forceinline__ float bperm_f(int byteaddr, float v) {
  return __builtin_bit_cast(
      float, __builtin_amdgcn_ds_bpermute(byteaddr, __builtin_bit_cast(int, v)));
}

} // namespace

extern "C" __global__ __launch_bounds__(256, 4) void rnn2_fp32(
    const float* __restrict__ x,
    const float* __restrict__ w_ih0,
    const float* __restrict__ w_hh0,
    const float* __restrict__ b_ih0,
    const float* __restrict__ b_hh0,
    const float* __restrict__ w_ih1,
    const float* __restrict__ w_hh1,
    const float* __restrict__ b_ih1,
    const float* __restrict__ b_hh1,
    const float* __restrict__ w_out,
    const float* __restrict__ b_out,
    float* __restrict__ out) {
  const int tid = (int)threadIdx.x;
  const int lane = tid & 63;
  const int wv = tid >> 6;         // wave index in block; one batch row per wave
  const int j = lane & 31;         // output element this lane owns
  const int half = lane >> 5;      // 0: k=0..15, 1: k=16..31
  const int row = (int)blockIdx.x * kWavesPerBlock + wv;

  __shared__ float hs0[kWavesPerBlock][kH];
  __shared__ float hs1[kWavesPerBlock][kH];

  // Per-lane HALF weight rows: lane j holds W[j][half*16 .. half*16+15].
  float whh0[kHalf], wih1[kHalf], whh1[kHalf];
  {
    const int wbase = j * kH + half * kHalf;
    const float* p0 = w_hh0 + wbase;
    const float* p1 = w_ih1 + wbase;
    const float* p2 = w_hh1 + wbase;
#pragma unroll
    for (int q = 0; q < kHalf / 4; ++q) {
      f4a a = *reinterpret_cast<const f4a*>(p0 + 4 * q);
      f4a b = *reinterpret_cast<const f4a*>(p1 + 4 * q);
      f4a c = *reinterpret_cast<const f4a*>(p2 + 4 * q);
      whh0[4 * q + 0] = a.x; whh0[4 * q + 1] = a.y;
      whh0[4 * q + 2] = a.z; whh0[4 * q + 3] = a.w;
      wih1[4 * q + 0] = b.x; wih1[4 * q + 1] = b.y;
      wih1[4 * q + 2] = b.z; wih1[4 * q + 3] = b.w;
      whh1[4 * q + 0] = c.x; whh1[4 * q + 1] = c.y;
      whh1[4 * q + 2] = c.z; whh1[4 * q + 3] = c.w;
    }
  }
  const float wih0_j = w_ih0[j];        // w_ih0 is [H,1]
  const float c0 = b_ih0[j] + b_hh0[j];
  const float c1 = b_ih1[j] + b_hh1[j];
  const float wout_j = w_out[j];        // w_out is [1,H]
  const float bout = b_out[0];

  // Replicated half hidden state: lane holds h[k] for k in its half.
  float h0[kHalf], h1[kHalf];
#pragma unroll
  for (int k = 0; k < kHalf; ++k) {
    h0[k] = 0.f;
    h1[k] = 0.f;
  }

  const int xaddr = ((lane ^ 32) << 2); // ds_bpermute byte address: other half
  const float* xrow = x + (long)row * kT;
  float* orow = out + (long)row * kT;

  for (int t0 = 0; t0 < kT; t0 += 64) {
    const float xv = xrow[t0 + lane];  // 64 timesteps staged in one VGPR
    float outv = 0.f;
#pragma unroll 4
    for (int tt = 0; tt < 64; ++tt) {
      const float xt = readlane_f(xv, tt); // wave-uniform x_t (SGPR)

      // ---- layer 0: h0 = tanh(x*w_ih0 + c0 + W_hh0 @ h0) ----
      float a0 = 0.f, a1 = 0.f, a2 = 0.f, a3 = 0.f;
#pragma unroll
      for (int k = 0; k < kHalf; k += 4) {
        a0 = fmaf(whh0[k + 0], h0[k + 0], a0);
        a1 = fmaf(whh0[k + 1], h0[k + 1], a1);
        a2 = fmaf(whh0[k + 2], h0[k + 2], a2);
        a3 = fmaf(whh0[k + 3], h0[k + 3], a3);
      }
      float p = (a0 + a1) + (a2 + a3);
      p += bperm_f(xaddr, p);                 // combine half-dots across lane^32
      p += fmaf(xt, wih0_j, c0);              // add x/bias once (post-combine)
      const float h0n = fast_tanh(p);

      // all-gather h0new (half per lane): 1 write + 4 broadcast b128 reads
      hs0[wv][j] = h0n;
      asm volatile("s_waitcnt lgkmcnt(0)" ::: "memory");
#pragma unroll
      for (int q = 0; q < kHalf / 4; ++q) {
        f4a v = *reinterpret_cast<const f4a*>(&hs0[wv][half * kHalf + 4 * q]);
        h0[4 * q + 0] = v.x; h0[4 * q + 1] = v.y;
        h0[4 * q + 2] = v.z; h0[4 * q + 3] = v.w;
      }

      // ---- layer 1: h1 = tanh(W_ih1 @ h0new + c1 + W_hh1 @ h1) ----
      float b0 = 0.f, b1 = 0.f, b2 = 0.f, b3 = 0.f;
#pragma unroll
      for (int k = 0; k < kHalf; k += 4) {
        b0 = fmaf(wih1[k + 0], h0[k + 0], b0);
        b1 = fmaf(wih1[k + 1], h0[k + 1], b1);
        b2 = fmaf(wih1[k + 2], h0[k + 2], b2);
        b3 = fmaf(wih1[k + 3], h0[k + 3], b3);
      }
#pragma unroll
      for (int k = 0; k < kHalf; k += 4) {
        b0 = fmaf(whh1[k + 0], h1[k + 0], b0);
        b1 = fmaf(whh1[k + 1], h1[k + 1], b1);
        b2 = fmaf(whh1[k + 2], h1[k + 2], b2);
        b3 = fmaf(whh1[k + 3], h1[k + 3], b3);
      }
      float s = (b0 + b1) + (b2 + b3);
      s += bperm_f(xaddr, s);
      s += c1;
      const float h1n = fast_tanh(s);

      // issue h1 gather write early; out-reduce overlaps its latency
      hs1[wv][j] = h1n;

      // ---- out_t = w_out . h1new + b_out (32-wide reduce, dup across halves)
      float o = wout_j * h1n;
      o = dpp_add<0x121>(o); // row_ror:1
      o = dpp_add<0x122>(o); // row_ror:2
      o = dpp_add<0x124>(o); // row_ror:4
      o = dpp_add<0x128>(o); // row_ror:8  -> sum within each 16-lane row
      {
        int si = __builtin_amdgcn_ds_swizzle(__builtin_bit_cast(int, o), 0x401F);
        o += __builtin_bit_cast(float, si);   // xor-16 within each half
      }
      o += bout;
      outv = (lane == tt) ? o : outv;         // lane tt keeps step t0+tt

      asm volatile("s_waitcnt lgkmcnt(0)" ::: "memory");
#pragma unroll
      for (int q = 0; q < kHalf / 4; ++q) {
        f4a v = *reinterpret_cast<const f4a*>(&hs1[wv][half * kHalf + 4 * q]);
        h1[4 * q + 0] = v.x; h1[4 * q + 1] = v.y;
        h1[4 * q + 2] = v.z; h1[4 * q + 3] = v.w;
      }
    }
    orow[t0 + lane] = outv;  // coalesced 256B store per wave per 64 steps
  }
}

extern "C" void kernel_launch(void* const* d_in, const int* in_sizes, int n_in,
                              void* d_out, int out_size, void* d_ws, size_t ws_size,
                              hipStream_t stream) {
  (void)in_sizes; (void)n_in; (void)d_ws; (void)ws_size; (void)out_size;
  const float* xp = (const float*)d_in[0];
  const float* w_ih0 = (const float*)d_in[1];
  const float* w_hh0 = (const float*)d_in[2];
  const float* b_ih0 = (const float*)d_in[3];
  const float* b_hh0 = (const float*)d_in[4];
  const float* w_ih1 = (const float*)d_in[5];
  const float* w_hh1 = (const float*)d_in[6];
  const float* b_ih1 = (const float*)d_in[7];
  const float* b_hh1 = (const float*)d_in[8];
  const float* w_out = (const float*)d_in[9];
  const float* b_out = (const float*)d_in[10];
  // d_in[11] = future (always 0 in this harness)

  dim3 grid(kB / kWavesPerBlock); // 1024 blocks, one row per wave
  dim3 block(kWavesPerBlock * 64);
  hipLaunchKernelGGL(rnn2_fp32, grid, block, 0, stream,
                     xp, w_ih0, w_hh0, b_ih0, b_hh0,
                     w_ih1, w_hh1, b_ih1, b_hh1,
                     w_out, b_out, (float*)d_out);
}

// Round 3
// 956.743 us; speedup vs baseline: 1.3395x; 1.3395x over previous
//
#include <hip/hip_runtime.h>
#include <stdint.h>

typedef float f32x4 __attribute__((ext_vector_type(4)));
typedef __bf16 bf16x8 __attribute__((ext_vector_type(8)));

namespace {

constexpr int kB = 4096;
constexpr int kT = 2048;

union FragU { uint32_t u[4]; bf16x8 v; };

__device__ __forceinline__ uint32_t pk_bf16(float a, float b) {
  uint32_t w;
  asm("v_cvt_pk_bf16_f32 %0, %1, %2" : "=v"(w) : "v"(a), "v"(b));
  return w;  // bf16(a) in [15:0], bf16(b) in [31:16]
}
__device__ __forceinline__ float bf_lo(uint32_t w) {
  return __builtin_bit_cast(float, (uint32_t)(w << 16));
}
__device__ __forceinline__ float bf_hi(uint32_t w) {
  return __builtin_bit_cast(float, (uint32_t)(w & 0xFFFF0000u));
}

__device__ __forceinline__ float fast_tanh(float x) {
  float e = __builtin_amdgcn_exp2f(x * 2.8853900817779268f);  // 2*log2(e)
  float r = __builtin_amdgcn_rcpf(e + 1.0f);
  return fmaf(-2.0f, r, 1.0f);
}

// Split 8 f32 into a bf16-hi fragment and bf16-lo (residual) fragment.
__device__ __forceinline__ void split8(const float* h, FragU& hi, FragU& lo) {
#pragma unroll
  for (int q = 0; q < 4; ++q) {
    float a = h[2 * q], b = h[2 * q + 1];
    uint32_t w = pk_bf16(a, b);
    hi.u[q] = w;
    lo.u[q] = pk_bf16(a - bf_lo(w), b - bf_hi(w));
  }
}

// A-fragment of W (rows permuted: tile t, m-row m -> j = 8*(m>>2) + 4*t + (m&3)).
// Lane holds W[j][8*(lane>>4) + 0..7] split into hi/lo bf16 fragments.
__device__ __forceinline__ void loadfrag(const float* W, int tile, int lane,
                                         FragU& hi, FragU& lo) {
  const int m = lane & 15, g = lane >> 4;
  const int j = 8 * (m >> 2) + 4 * tile + (m & 3);
  const float* p = W + j * 32 + 8 * g;
  float w8[8];
#pragma unroll
  for (int q = 0; q < 2; ++q) {
    float4 t = ((const float4*)p)[q];
    w8[4 * q + 0] = t.x; w8[4 * q + 1] = t.y;
    w8[4 * q + 2] = t.z; w8[4 * q + 3] = t.w;
  }
  split8(w8, hi, lo);
}

__device__ __forceinline__ f32x4 mfma(bf16x8 a, bf16x8 b, f32x4 c) {
  return __builtin_amdgcn_mfma_f32_16x16x32_bf16(a, b, c, 0, 0, 0);
}

}  // namespace

extern "C" __global__ __launch_bounds__(64, 1) void rnn2_mfma(
    const float* __restrict__ x,
    const float* __restrict__ w_ih0,
    const float* __restrict__ w_hh0,
    const float* __restrict__ b_ih0,
    const float* __restrict__ b_hh0,
    const float* __restrict__ w_ih1,
    const float* __restrict__ w_hh1,
    const float* __restrict__ b_ih1,
    const float* __restrict__ b_hh1,
    const float* __restrict__ w_out,
    const float* __restrict__ b_out,
    float* __restrict__ out) {
  const int lane = (int)threadIdx.x;  // 1 wave per block
  const int g = lane >> 4;            // k-slice / dup group
  const int m = lane & 15;            // batch-row within tile
  const int rg = (int)blockIdx.x * 16 + m;

  // ---- persistent weight fragments (hi/lo split-bf16), loaded once ----
  FragU Ahh0h[2], Ahh0l[2], Aih1h[2], Aih1l[2], Ahh1h[2], Ahh1l[2];
#pragma unroll
  for (int t = 0; t < 2; ++t) {
    loadfrag(w_hh0, t, lane, Ahh0h[t], Ahh0l[t]);
    loadfrag(w_ih1, t, lane, Aih1h[t], Aih1l[t]);
    loadfrag(w_hh1, t, lane, Ahh1h[t], Ahh1l[t]);
  }

  // Per-reg constants, j = 8*g + i for reg slot i (z0 regs: i 0..3, z1: 4..7).
  float c0v[8], c1v[8], woutv[8], wih0v[8];
#pragma unroll
  for (int i = 0; i < 8; ++i) {
    int jj = 8 * g + i;
    c0v[i] = b_ih0[jj] + b_hh0[jj];
    c1v[i] = b_ih1[jj] + b_hh1[jj];
    woutv[i] = w_out[jj];
    wih0v[i] = w_ih0[jj];
  }
  const float bout0 = (g == 0) ? b_out[0] : 0.0f;  // folded into group-0 partial

  // Hidden state as next-step B-fragments (hi/lo), start at zero.
  FragU h0h, h0l, h1h, h1l;
#pragma unroll
  for (int q = 0; q < 4; ++q) { h0h.u[q] = 0; h0l.u[q] = 0; h1h.u[q] = 0; h1l.u[q] = 0; }

  const float* xr = x + (long)rg * kT;
  float* orow = out + (long)rg * kT;

  for (int tb = 0; tb < kT; tb += 16) {
    float4 xq0 = ((const float4*)(xr + tb))[0];
    float4 xq1 = ((const float4*)(xr + tb))[1];
    float4 xq2 = ((const float4*)(xr + tb))[2];
    float4 xq3 = ((const float4*)(xr + tb))[3];
    float xc[16] = {xq0.x, xq0.y, xq0.z, xq0.w, xq1.x, xq1.y, xq1.z, xq1.w,
                    xq2.x, xq2.y, xq2.z, xq2.w, xq3.x, xq3.y, xq3.z, xq3.w};
    float stash[16];

#pragma unroll
    for (int i = 0; i < 16; ++i) {
      const float xt = xc[i];

      // ---- layer 0: Z^T = Whh0 * h0^T + x*w_ih0 + c0 ----
      f32x4 z0 = {fmaf(xt, wih0v[0], c0v[0]), fmaf(xt, wih0v[1], c0v[1]),
                  fmaf(xt, wih0v[2], c0v[2]), fmaf(xt, wih0v[3], c0v[3])};
      f32x4 z1 = {fmaf(xt, wih0v[4], c0v[4]), fmaf(xt, wih0v[5], c0v[5]),
                  fmaf(xt, wih0v[6], c0v[6]), fmaf(xt, wih0v[7], c0v[7])};
      z0 = mfma(Ahh0h[0].v, h0l.v, z0);
      z0 = mfma(Ahh0l[0].v, h0h.v, z0);
      z0 = mfma(Ahh0h[0].v, h0h.v, z0);
      z1 = mfma(Ahh0h[1].v, h0l.v, z1);
      z1 = mfma(Ahh0l[1].v, h0h.v, z1);
      z1 = mfma(Ahh0h[1].v, h0h.v, z1);

      float h0f[8] = {fast_tanh(z0[0]), fast_tanh(z0[1]), fast_tanh(z0[2]),
                      fast_tanh(z0[3]), fast_tanh(z1[0]), fast_tanh(z1[1]),
                      fast_tanh(z1[2]), fast_tanh(z1[3])};
      split8(h0f, h0h, h0l);  // h0(t) -> B-fragment for layer1 and next step

      // ---- layer 1: Wih1 * h0(t)^T + Whh1 * h1(t-1)^T + c1 ----
      f32x4 y0 = {c1v[0], c1v[1], c1v[2], c1v[3]};
      f32x4 y1 = {c1v[4], c1v[5], c1v[6], c1v[7]};
      y0 = mfma(Aih1h[0].v, h0l.v, y0);
      y0 = mfma(Aih1l[0].v, h0h.v, y0);
      y0 = mfma(Aih1h[0].v, h0h.v, y0);
      y0 = mfma(Ahh1h[0].v, h1l.v, y0);
      y0 = mfma(Ahh1l[0].v, h1h.v, y0);
      y0 = mfma(Ahh1h[0].v, h1h.v, y0);
      y1 = mfma(Aih1h[1].v, h0l.v, y1);
      y1 = mfma(Aih1l[1].v, h0h.v, y1);
      y1 = mfma(Aih1h[1].v, h0h.v, y1);
      y1 = mfma(Ahh1h[1].v, h1l.v, y1);
      y1 = mfma(Ahh1l[1].v, h1h.v, y1);
      y1 = mfma(Ahh1h[1].v, h1h.v, y1);

      float h1f[8] = {fast_tanh(y0[0]), fast_tanh(y0[1]), fast_tanh(y0[2]),
                      fast_tanh(y0[3]), fast_tanh(y1[0]), fast_tanh(y1[1]),
                      fast_tanh(y1[2]), fast_tanh(y1[3])};
      split8(h1f, h1h, h1l);

      // ---- out partial: this lane's 8 j-slots (group sum deferred) ----
      float o = fmaf(woutv[0], h1f[0], bout0);
      o = fmaf(woutv[1], h1f[1], o);
      o = fmaf(woutv[2], h1f[2], o);
      o = fmaf(woutv[3], h1f[3], o);
      o = fmaf(woutv[4], h1f[4], o);
      o = fmaf(woutv[5], h1f[5], o);
      o = fmaf(woutv[6], h1f[6], o);
      o = fmaf(woutv[7], h1f[7], o);
      stash[i] = o;
    }

    // Batched cross-group reduce (off the recurrence critical path).
#pragma unroll
    for (int i = 0; i < 16; ++i) {
      float s = stash[i];
      s += __shfl_xor(s, 16, 64);
      s += __shfl_xor(s, 32, 64);
      stash[i] = s;
    }
    if (g == ((tb >> 4) & 3)) {  // one dup group stores this block
      ((float4*)(orow + tb))[0] = make_float4(stash[0], stash[1], stash[2], stash[3]);
      ((float4*)(orow + tb))[1] = make_float4(stash[4], stash[5], stash[6], stash[7]);
      ((float4*)(orow + tb))[2] = make_float4(stash[8], stash[9], stash[10], stash[11]);
      ((float4*)(orow + tb))[3] = make_float4(stash[12], stash[13], stash[14], stash[15]);
    }
  }
}

extern "C" void kernel_launch(void* const* d_in, const int* in_sizes, int n_in,
                              void* d_out, int out_size, void* d_ws, size_t ws_size,
                              hipStream_t stream) {
  (void)in_sizes; (void)n_in; (void)d_ws; (void)ws_size; (void)out_size;
  const float* xp = (const float*)d_in[0];
  const float* w_ih0 = (const float*)d_in[1];
  const float* w_hh0 = (const float*)d_in[2];
  const float* b_ih0 = (const float*)d_in[3];
  const float* b_hh0 = (const float*)d_in[4];
  const float* w_ih1 = (const float*)d_in[5];
  const float* w_hh1 = (const float*)d_in[6];
  const float* b_ih1 = (const float*)d_in[7];
  const float* b_hh1 = (const float*)d_in[8];
  const float* w_out = (const float*)d_in[9];
  const float* b_out = (const float*)d_in[10];
  // d_in[11] = future (0 in this harness)

  dim3 grid(kB / 16);  // 256 blocks = 256 waves, one 16-row tile each
  dim3 block(64);
  hipLaunchKernelGGL(rnn2_mfma, grid, block, 0, stream,
                     xp, w_ih0, w_hh0, b_ih0, b_hh0,
                     w_ih1, w_hh1, b_ih1, b_hh1,
                     w_out, b_out, (float*)d_out);
}

// Round 5
// 790.929 us; speedup vs baseline: 1.6203x; 1.2096x over previous
//
#include <hip/hip_runtime.h>
#include <stdint.h>

typedef float f32x4 __attribute__((ext_vector_type(4)));
typedef _Float16 f16x8 __attribute__((ext_vector_type(8)));
typedef _Float16 f16x2 __attribute__((ext_vector_type(2)));

namespace {

constexpr int kB = 4096;
constexpr int kT = 2048;

union Frag {
  f16x2 h2[4];
  f16x8 v;
};

__device__ __forceinline__ float fast_tanh(float x) {
  // tanh(x) = 1 - 2/(exp(2x)+1)
  float e = __builtin_amdgcn_exp2f(x * 2.8853900817779268f);  // 2*log2(e)
  float r = __builtin_amdgcn_rcpf(e + 1.0f);
  return fmaf(-2.0f, r, 1.0f);
}

__device__ __forceinline__ f16x2 pk(float a, float b) {
  return __builtin_bit_cast(f16x2, __builtin_amdgcn_cvt_pkrtz(a, b));
}

// A-fragment of W, rows permuted so D-regs align with next B-frag k-slices:
// tile t, D-row i -> j = 8*(i>>2) + 4*t + (i&3); lane(m,g) holds W[j(m)][8g..8g+7]
// split into f16 hi + residual lo.
__device__ __forceinline__ void loadfrag(const float* W, int tile, int lane,
                                         Frag& hi, Frag& lo) {
  const int m = lane & 15, g = lane >> 4;
  const int j = 8 * (m >> 2) + 4 * tile + (m & 3);
  const float* p = W + j * 32 + 8 * g;
  float w8[8];
#pragma unroll
  for (int q = 0; q < 2; ++q) {
    float4 t = ((const float4*)p)[q];
    w8[4 * q + 0] = t.x; w8[4 * q + 1] = t.y;
    w8[4 * q + 2] = t.z; w8[4 * q + 3] = t.w;
  }
#pragma unroll
  for (int q = 0; q < 4; ++q) {
    float a = w8[2 * q], b = w8[2 * q + 1];
    f16x2 h = pk(a, b);
    hi.h2[q] = h;
    lo.h2[q] = pk(a - (float)h.x, b - (float)h.y);
  }
}

__device__ __forceinline__ f32x4 mfma(f16x8 a, f16x8 b, f32x4 c) {
  return __builtin_amdgcn_mfma_f32_16x16x32_f16(a, b, c, 0, 0, 0);
}

}  // namespace

extern "C" __global__ __launch_bounds__(64, 1) void rnn2_mfma16(
    const float* __restrict__ x,
    const float* __restrict__ w_ih0,
    const float* __restrict__ w_hh0,
    const float* __restrict__ b_ih0,
    const float* __restrict__ b_hh0,
    const float* __restrict__ w_ih1,
    const float* __restrict__ w_hh1,
    const float* __restrict__ b_ih1,
    const float* __restrict__ b_hh1,
    const float* __restrict__ w_out,
    const float* __restrict__ b_out,
    float* __restrict__ out) {
  const int lane = (int)threadIdx.x;  // one wave per block
  const int g = lane >> 4;            // k-slice group
  const int m = lane & 15;            // batch col within tile
  const int rg = (int)blockIdx.x * 16 + m;

  // ---- persistent weight fragments (f16 hi + residual lo) ----
  Frag Whh0h[2], Whh0l[2], Wih1h[2], Wih1l[2], Whh1h[2], Whh1l[2];
#pragma unroll
  for (int t = 0; t < 2; ++t) {
    loadfrag(w_hh0, t, lane, Whh0h[t], Whh0l[t]);
    loadfrag(w_ih1, t, lane, Wih1h[t], Wih1l[t]);
    loadfrag(w_hh1, t, lane, Whh1h[t], Whh1l[t]);
  }

  // w_out as A-row 0 only: lane(m,g) holds w_out[8g+e] if m==0 else 0.
  Frag Awout;
#pragma unroll
  for (int q = 0; q < 4; ++q) {
    float a = (m == 0) ? w_out[8 * g + 2 * q] : 0.f;
    float b = (m == 0) ? w_out[8 * g + 2 * q + 1] : 0.f;
    Awout.h2[q] = pk(a, b);
  }

  // Per-reg constants; reg slot i (tiles z0:i=0..3, z1:i=4..7) <-> j = 8g+i.
  float c0v[8], c1v[8], wih0v[8];
#pragma unroll
  for (int i = 0; i < 8; ++i) {
    int jj = 8 * g + i;
    c0v[i] = b_ih0[jj] + b_hh0[jj];
    c1v[i] = b_ih1[jj] + b_hh1[jj];
    wih0v[i] = w_ih0[jj];  // [H,1]
  }
  const f32x4 coutInit = {(g == 0) ? b_out[0] : 0.f, 0.f, 0.f, 0.f};

  // Hidden state as B-fragments (single f16), zero-init.
  Frag h0, h1;
#pragma unroll
  for (int q = 0; q < 4; ++q) { h0.h2[q] = pk(0.f, 0.f); h1.h2[q] = pk(0.f, 0.f); }

  const float* xr = x + (long)rg * kT;
  float* orow = out + (long)rg * kT;

  for (int tb = 0; tb < kT; tb += 16) {
    float4 xq0 = ((const float4*)(xr + tb))[0];
    float4 xq1 = ((const float4*)(xr + tb))[1];
    float4 xq2 = ((const float4*)(xr + tb))[2];
    float4 xq3 = ((const float4*)(xr + tb))[3];
    float xc[16] = {xq0.x, xq0.y, xq0.z, xq0.w, xq1.x, xq1.y, xq1.z, xq1.w,
                    xq2.x, xq2.y, xq2.z, xq2.w, xq3.x, xq3.y, xq3.z, xq3.w};
    float stash[16];

#pragma unroll
    for (int i = 0; i < 16; ++i) {
      const float xt = xc[i];

      // ---- layer1 B-part first: uses PREVIOUS h1 (fills pipe early) ----
      f32x4 y0 = {c1v[0], c1v[1], c1v[2], c1v[3]};
      f32x4 y1 = {c1v[4], c1v[5], c1v[6], c1v[7]};
      y0 = mfma(Whh1h[0].v, h1.v, y0);
      y1 = mfma(Whh1h[1].v, h1.v, y1);
      y0 = mfma(Whh1l[0].v, h1.v, y0);
      y1 = mfma(Whh1l[1].v, h1.v, y1);

      // ---- layer0: z = Whh0*h0 + (x*wih0 + c0) ----
      f32x4 z0 = {fmaf(xt, wih0v[0], c0v[0]), fmaf(xt, wih0v[1], c0v[1]),
                  fmaf(xt, wih0v[2], c0v[2]), fmaf(xt, wih0v[3], c0v[3])};
      f32x4 z1 = {fmaf(xt, wih0v[4], c0v[4]), fmaf(xt, wih0v[5], c0v[5]),
                  fmaf(xt, wih0v[6], c0v[6]), fmaf(xt, wih0v[7], c0v[7])};
      z0 = mfma(Whh0h[0].v, h0.v, z0);
      z1 = mfma(Whh0h[1].v, h0.v, z1);
      z0 = mfma(Whh0l[0].v, h0.v, z0);
      z1 = mfma(Whh0l[1].v, h0.v, z1);

      const float h0f0 = fast_tanh(z0[0]), h0f1 = fast_tanh(z0[1]);
      const float h0f2 = fast_tanh(z0[2]), h0f3 = fast_tanh(z0[3]);
      const float h0f4 = fast_tanh(z1[0]), h0f5 = fast_tanh(z1[1]);
      const float h0f6 = fast_tanh(z1[2]), h0f7 = fast_tanh(z1[3]);
      h0.h2[0] = pk(h0f0, h0f1);
      h0.h2[1] = pk(h0f2, h0f3);
      h0.h2[2] = pk(h0f4, h0f5);
      h0.h2[3] = pk(h0f6, h0f7);

      // ---- layer1 A-part: chain onto yB with fresh h0 ----
      y0 = mfma(Wih1h[0].v, h0.v, y0);
      y1 = mfma(Wih1h[1].v, h0.v, y1);
      y0 = mfma(Wih1l[0].v, h0.v, y0);
      y1 = mfma(Wih1l[1].v, h0.v, y1);

      const float h1f0 = fast_tanh(y0[0]), h1f1 = fast_tanh(y0[1]);
      const float h1f2 = fast_tanh(y0[2]), h1f3 = fast_tanh(y0[3]);
      const float h1f4 = fast_tanh(y1[0]), h1f5 = fast_tanh(y1[1]);
      const float h1f6 = fast_tanh(y1[2]), h1f7 = fast_tanh(y1[3]);
      h1.h2[0] = pk(h1f0, h1f1);
      h1.h2[1] = pk(h1f2, h1f3);
      h1.h2[2] = pk(h1f4, h1f5);
      h1.h2[3] = pk(h1f6, h1f7);

      // ---- out_t = w_out . h1 + b_out via 1 MFMA (D row 0 = lanes 0..15 reg0)
      f32x4 od = mfma(Awout.v, h1.v, coutInit);
      stash[i] = od[0];
    }

    if (lane < 16) {  // lane m holds out[rg][tb..tb+15]
      ((float4*)(orow + tb))[0] = make_float4(stash[0], stash[1], stash[2], stash[3]);
      ((float4*)(orow + tb))[1] = make_float4(stash[4], stash[5], stash[6], stash[7]);
      ((float4*)(orow + tb))[2] = make_float4(stash[8], stash[9], stash[10], stash[11]);
      ((float4*)(orow + tb))[3] = make_float4(stash[12], stash[13], stash[14], stash[15]);
    }
  }
}

extern "C" void kernel_launch(void* const* d_in, const int* in_sizes, int n_in,
                              void* d_out, int out_size, void* d_ws, size_t ws_size,
                              hipStream_t stream) {
  (void)in_sizes; (void)n_in; (void)d_ws; (void)ws_size; (void)out_size;
  const float* xp = (const float*)d_in[0];
  const float* w_ih0 = (const float*)d_in[1];
  const float* w_hh0 = (const float*)d_in[2];
  const float* b_ih0 = (const float*)d_in[3];
  const float* b_hh0 = (const float*)d_in[4];
  const float* w_ih1 = (const float*)d_in[5];
  const float* w_hh1 = (const float*)d_in[6];
  const float* b_ih1 = (const float*)d_in[7];
  const float* b_hh1 = (const float*)d_in[8];
  const float* w_out = (const float*)d_in[9];
  const float* b_out = (const float*)d_in[10];
  // d_in[11] = future (0 in this harness)

  dim3 grid(kB / 16);  // 256 waves, one 16-row batch tile each
  dim3 block(64);
  hipLaunchKernelGGL(rnn2_mfma16, grid, block, 0, stream,
                     xp, w_ih0, w_hh0, b_ih0, b_hh0,
                     w_ih1, w_hh1, b_ih1, b_hh1,
                     w_out, b_out, (float*)d_out);
}

// Round 6
// 508.017 us; speedup vs baseline: 2.5227x; 1.5569x over previous
//
#include <hip/hip_runtime.h>
#include <stdint.h>

typedef float f32x4 __attribute__((ext_vector_type(4)));
typedef _Float16 f16x8 __attribute__((ext_vector_type(8)));
typedef _Float16 f16x2 __attribute__((ext_vector_type(2)));

namespace {

constexpr int kB = 4096;
constexpr int kT = 2048;
constexpr int kNSB = kT / 16;                    // 128 superblocks of 16 steps
constexpr float kS = 2.8853900817779268f;        // 2*log2(e), folded into weights

union Frag { f16x2 h2[4]; f16x8 v; uint32_t u[4]; };

__device__ __forceinline__ f16x2 pk(float a, float b) {
  return __builtin_bit_cast(f16x2, __builtin_amdgcn_cvt_pkrtz(a, b));
}
// tanh from pre-scaled argument zs = 2*log2e*z : tanh = 1 - 2/(2^zs + 1)
__device__ __forceinline__ float tanh_ps(float zs) {
  float e = __builtin_amdgcn_exp2f(zs);
  float r = __builtin_amdgcn_rcpf(e + 1.0f);
  return fmaf(-2.0f, r, 1.0f);
}
__device__ __forceinline__ f32x4 mfma(f16x8 a, f16x8 b, f32x4 c) {
  return __builtin_amdgcn_mfma_f32_16x16x32_f16(a, b, c, 0, 0, 0);
}

// A-fragment with permuted rows (tile t, D-row i -> j = 8*(i>>2)+4t+(i&3)),
// scaled by `scale`, split into f16 hi + residual lo.  (layout proven in R5)
__device__ __forceinline__ void loadfrag_hl(const float* W, int tile, int lane,
                                            float scale, Frag& hi, Frag& lo) {
  const int m = lane & 15, g = lane >> 4;
  const int j = 8 * (m >> 2) + 4 * tile + (m & 3);
  const float* p = W + j * 32 + 8 * g;
  float w8[8];
#pragma unroll
  for (int q = 0; q < 2; ++q) {
    float4 t = ((const float4*)p)[q];
    w8[4 * q + 0] = t.x * scale; w8[4 * q + 1] = t.y * scale;
    w8[4 * q + 2] = t.z * scale; w8[4 * q + 3] = t.w * scale;
  }
#pragma unroll
  for (int q = 0; q < 4; ++q) {
    float a = w8[2 * q], b = w8[2 * q + 1];
    f16x2 h = pk(a, b);
    hi.h2[q] = h;
    lo.h2[q] = pk(a - (float)h.x, b - (float)h.y);
  }
}
__device__ __forceinline__ void loadfrag_hi(const float* W, int tile, int lane,
                                            float scale, Frag& hi) {
  Frag lo;
  loadfrag_hl(W, tile, lane, scale, hi, lo);
  (void)lo;
}

}  // namespace

extern "C" __global__ __launch_bounds__(128, 1) void rnn2_pipe(
    const float* __restrict__ x,
    const float* __restrict__ w_ih0,
    const float* __restrict__ w_hh0,
    const float* __restrict__ b_ih0,
    const float* __restrict__ b_hh0,
    const float* __restrict__ w_ih1,
    const float* __restrict__ w_hh1,
    const float* __restrict__ b_ih1,
    const float* __restrict__ b_hh1,
    const float* __restrict__ w_out,
    const float* __restrict__ b_out,
    float* __restrict__ out) {
  const int tid = (int)threadIdx.x;
  const int role = tid >> 6;   // wave 0 = layer0 producer (A), wave 1 = layer1 consumer (B)
  const int lane = tid & 63;
  const int g = lane >> 4;
  const int m = lane & 15;
  const int rg = (int)blockIdx.x * 16 + m;

  // h0 ring buffer: [slot][batch col][j], f16.  8 slots x 1KB = 8KB.
  __shared__ __align__(16) _Float16 hbuf[8][16][32];

  // ---- role-specific persistent state ----
  Frag Wh[2], Wl[2];      // A: Whh0 hi/lo (scaled)
  Frag Bh1[2], Bi1[2];    // B: Whh1 hi, Wih1 hi (scaled)
  float cv[8];            // A: scaled c0 ; B: scaled c1   (slot i <-> j = 8g+i)
  float wih0v[8];         // A (scaled)
  float woutv[8];         // B (unscaled)
  float bout = 0.f;
  Frag h0, h1;            // A's h0 frag; B's h1 frag
#pragma unroll
  for (int q = 0; q < 4; ++q) { h0.u[q] = 0; h1.u[q] = 0; }

  if (role == 0) {
#pragma unroll
    for (int t = 0; t < 2; ++t) loadfrag_hl(w_hh0, t, lane, kS, Wh[t], Wl[t]);
#pragma unroll
    for (int i = 0; i < 8; ++i) {
      int jj = 8 * g + i;
      cv[i] = (b_ih0[jj] + b_hh0[jj]) * kS;
      wih0v[i] = w_ih0[jj] * kS;
    }
  } else {
#pragma unroll
    for (int t = 0; t < 2; ++t) {
      loadfrag_hi(w_hh1, t, lane, kS, Bh1[t]);
      loadfrag_hi(w_ih1, t, lane, kS, Bi1[t]);
    }
#pragma unroll
    for (int i = 0; i < 8; ++i) {
      int jj = 8 * g + i;
      cv[i] = (b_ih1[jj] + b_hh1[jj]) * kS;
      woutv[i] = w_out[jj];
    }
    bout = b_out[0];
  }

  const float* xrow = x + (long)rg * kT;
  float* orow = out + (long)rg * kT;

  // ---- wave A: one layer-0 step; writes h0(t) to slot ----
  auto stepA = [&](float xt, int slot) {
    f32x4 z0i = {fmaf(xt, wih0v[0], cv[0]), fmaf(xt, wih0v[1], cv[1]),
                 fmaf(xt, wih0v[2], cv[2]), fmaf(xt, wih0v[3], cv[3])};
    f32x4 z1i = {fmaf(xt, wih0v[4], cv[4]), fmaf(xt, wih0v[5], cv[5]),
                 fmaf(xt, wih0v[6], cv[6]), fmaf(xt, wih0v[7], cv[7])};
    f32x4 zz = {0.f, 0.f, 0.f, 0.f};
    f32x4 z0a = mfma(Wh[0].v, h0.v, z0i);
    f32x4 z0b = mfma(Wl[0].v, h0.v, zz);
    f32x4 z1a = mfma(Wh[1].v, h0.v, z1i);
    f32x4 z1b = mfma(Wl[1].v, h0.v, zz);
    float f0 = tanh_ps(z0a[0] + z0b[0]), f1 = tanh_ps(z0a[1] + z0b[1]);
    float f2 = tanh_ps(z0a[2] + z0b[2]), f3 = tanh_ps(z0a[3] + z0b[3]);
    float f4 = tanh_ps(z1a[0] + z1b[0]), f5 = tanh_ps(z1a[1] + z1b[1]);
    float f6 = tanh_ps(z1a[2] + z1b[2]), f7 = tanh_ps(z1a[3] + z1b[3]);
    h0.h2[0] = pk(f0, f1); h0.h2[1] = pk(f2, f3);
    h0.h2[2] = pk(f4, f5); h0.h2[3] = pk(f6, f7);
    *reinterpret_cast<f16x8*>(&hbuf[slot][m][8 * g]) = h0.v;  // 16B, B-frag layout
  };

  float stash[16];
  // ---- wave B: one layer-1+out step from a prefetched h0 fragment ----
  auto stepB = [&](const Frag& hf, float* st) {
    f32x4 y0 = {cv[0], cv[1], cv[2], cv[3]};
    f32x4 y1 = {cv[4], cv[5], cv[6], cv[7]};
    y0 = mfma(Bh1[0].v, h1.v, y0);
    y1 = mfma(Bh1[1].v, h1.v, y1);
    y0 = mfma(Bi1[0].v, hf.v, y0);
    y1 = mfma(Bi1[1].v, hf.v, y1);
    float f0 = tanh_ps(y0[0]), f1 = tanh_ps(y0[1]);
    float f2 = tanh_ps(y0[2]), f3 = tanh_ps(y0[3]);
    float f4 = tanh_ps(y1[0]), f5 = tanh_ps(y1[1]);
    float f6 = tanh_ps(y1[2]), f7 = tanh_ps(y1[3]);
    h1.h2[0] = pk(f0, f1); h1.h2[1] = pk(f2, f3);
    h1.h2[2] = pk(f4, f5); h1.h2[3] = pk(f6, f7);
    float oa = fmaf(woutv[0], f0, woutv[1] * f1);
    float ob = fmaf(woutv[2], f2, woutv[3] * f3);
    oa = fmaf(woutv[4], f4, oa);
    ob = fmaf(woutv[5], f5, ob);
    oa = fmaf(woutv[6], f6, oa);
    ob = fmaf(woutv[7], f7, ob);
    float o = oa + ob;
    o += __shfl_xor(o, 16, 64);
    o += __shfl_xor(o, 32, 64);
    *st = o + bout;
  };

  auto readslot = [&](int slot) {
    Frag r;
    r.v = *reinterpret_cast<const f16x8*>(&hbuf[slot][m][8 * g]);
    return r;
  };

  auto storeblock = [&](int base) {
    if (lane < 16) {
      float4* dst = (float4*)(orow + base);
      dst[0] = make_float4(stash[0], stash[1], stash[2], stash[3]);
      dst[1] = make_float4(stash[4], stash[5], stash[6], stash[7]);
      dst[2] = make_float4(stash[8], stash[9], stash[10], stash[11]);
      dst[3] = make_float4(stash[12], stash[13], stash[14], stash[15]);
    }
  };

  // x staging (A only): current block xc, prefetched next block xn
  float xc[16], xn[16];
  if (role == 0) {
    float4 q0 = ((const float4*)xrow)[0], q1 = ((const float4*)xrow)[1];
    float4 q2 = ((const float4*)xrow)[2], q3 = ((const float4*)xrow)[3];
    xn[0]=q0.x; xn[1]=q0.y; xn[2]=q0.z; xn[3]=q0.w;
    xn[4]=q1.x; xn[5]=q1.y; xn[6]=q1.z; xn[7]=q1.w;
    xn[8]=q2.x; xn[9]=q2.y; xn[10]=q2.z; xn[11]=q2.w;
    xn[12]=q3.x; xn[13]=q3.y; xn[14]=q3.z; xn[15]=q3.w;
  }

  Frag pf0, pf1;  // B: prefetched h0 fragments for next phase
#pragma unroll
  for (int q = 0; q < 4; ++q) { pf0.u[q] = 0; pf1.u[q] = 0; }

  // Main pipeline: phase p handles A:{t=2p,2p+1}, B:{s=2p-4,2p-3}, B prefetch {2p-2,2p-1}.
  for (int sb = 0; sb < kNSB; ++sb) {
    if (role == 0) {
#pragma unroll
      for (int i = 0; i < 16; ++i) xc[i] = xn[i];
      const float* src = xrow + ((sb + 1 < kNSB) ? (sb + 1) : sb) * 16;
      float4 q0 = ((const float4*)src)[0], q1 = ((const float4*)src)[1];
      float4 q2 = ((const float4*)src)[2], q3 = ((const float4*)src)[3];
      xn[0]=q0.x; xn[1]=q0.y; xn[2]=q0.z; xn[3]=q0.w;
      xn[4]=q1.x; xn[5]=q1.y; xn[6]=q1.z; xn[7]=q1.w;
      xn[8]=q2.x; xn[9]=q2.y; xn[10]=q2.z; xn[11]=q2.w;
      xn[12]=q3.x; xn[13]=q3.y; xn[14]=q3.z; xn[15]=q3.w;
    }
#pragma unroll
    for (int ph = 0; ph < 8; ++ph) {
      if (role == 0) {
        stepA(xc[2 * ph], (2 * ph) & 7);
        stepA(xc[2 * ph + 1], (2 * ph + 1) & 7);
      } else {
        const int p = sb * 8 + ph;
        if (p >= 2) {
          stepB(pf0, &stash[(2 * ph - 4) & 15]);
          stepB(pf1, &stash[(2 * ph - 3) & 15]);
        }
        if (p >= 1) {
          pf0 = readslot((2 * ph - 2) & 7);
          pf1 = readslot((2 * ph - 1) & 7);
        }
        if (ph == 1 && sb >= 1) storeblock((sb - 1) * 16);
      }
      __syncthreads();
    }
  }

  // Epilogue: B drains the last 4 steps (all h0 writes already barrier-ordered).
  if (role == 1) {
    stepB(pf0, &stash[12]);          // s = 2044
    stepB(pf1, &stash[13]);          // s = 2045
    pf0 = readslot(2046 & 7);
    pf1 = readslot(2047 & 7);
    stepB(pf0, &stash[14]);          // s = 2046
    stepB(pf1, &stash[15]);          // s = 2047
    storeblock(kT - 16);
  }
}

extern "C" void kernel_launch(void* const* d_in, const int* in_sizes, int n_in,
                              void* d_out, int out_size, void* d_ws, size_t ws_size,
                              hipStream_t stream) {
  (void)in_sizes; (void)n_in; (void)d_ws; (void)ws_size; (void)out_size;
  const float* xp = (const float*)d_in[0];
  const float* w_ih0 = (const float*)d_in[1];
  const float* w_hh0 = (const float*)d_in[2];
  const float* b_ih0 = (const float*)d_in[3];
  const float* b_hh0 = (const float*)d_in[4];
  const float* w_ih1 = (const float*)d_in[5];
  const float* w_hh1 = (const float*)d_in[6];
  const float* b_ih1 = (const float*)d_in[7];
  const float* b_hh1 = (const float*)d_in[8];
  const float* w_out = (const float*)d_in[9];
  const float* b_out = (const float*)d_in[10];
  // d_in[11] = future (0 in this harness)

  dim3 grid(kB / 16);   // 256 blocks, one 16-row batch tile each
  dim3 block(128);      // 2 waves: layer0 producer + layer1 consumer
  hipLaunchKernelGGL(rnn2_pipe, grid, block, 0, stream,
                     xp, w_ih0, w_hh0, b_ih0, b_hh0,
                     w_ih1, w_hh1, b_ih1, b_hh1,
                     w_out, b_out, (float*)d_out);
}

// Round 7
// 419.606 us; speedup vs baseline: 3.0542x; 1.2107x over previous
//
#include <hip/hip_runtime.h>
#include <stdint.h>

typedef float f32x4 __attribute__((ext_vector_type(4)));
typedef _Float16 f16x8 __attribute__((ext_vector_type(8)));
typedef _Float16 f16x2 __attribute__((ext_vector_type(2)));

namespace {

constexpr int kB = 4096;
constexpr int kT = 2048;
constexpr int kNSB = kT / 16;                // 128 x-staging superblocks
constexpr int kPhases = kT / 4;              // 512 4-step phases
constexpr float kS = 2.8853900817779268f;    // 2*log2(e), folded into weights

union Frag { f16x2 h2[4]; f16x8 v; uint32_t u[4]; };

__device__ __forceinline__ f16x2 pk(float a, float b) {
  return __builtin_bit_cast(f16x2, __builtin_amdgcn_cvt_pkrtz(a, b));
}
// tanh from pre-scaled argument zs = 2*log2e*z : tanh = 1 - 2/(2^zs + 1)
__device__ __forceinline__ float tanh_ps(float zs) {
  float e = __builtin_amdgcn_exp2f(zs);
  float r = __builtin_amdgcn_rcpf(e + 1.0f);
  return fmaf(-2.0f, r, 1.0f);
}
__device__ __forceinline__ f32x4 mfma(f16x8 a, f16x8 b, f32x4 c) {
  return __builtin_amdgcn_mfma_f32_16x16x32_f16(a, b, c, 0, 0, 0);
}

// A-fragment with permuted rows (tile t, D-row i -> j = 8*(i>>2)+4t+(i&3)),
// scaled by `scale`, split into f16 hi + residual lo.  (layout proven R5/R6)
__device__ __forceinline__ void loadfrag_hl(const float* W, int tile, int lane,
                                            float scale, Frag& hi, Frag& lo) {
  const int m = lane & 15, g = lane >> 4;
  const int j = 8 * (m >> 2) + 4 * tile + (m & 3);
  const float* p = W + j * 32 + 8 * g;
  float w8[8];
#pragma unroll
  for (int q = 0; q < 2; ++q) {
    float4 t = ((const float4*)p)[q];
    w8[4 * q + 0] = t.x * scale; w8[4 * q + 1] = t.y * scale;
    w8[4 * q + 2] = t.z * scale; w8[4 * q + 3] = t.w * scale;
  }
#pragma unroll
  for (int q = 0; q < 4; ++q) {
    float a = w8[2 * q], b = w8[2 * q + 1];
    f16x2 h = pk(a, b);
    hi.h2[q] = h;
    lo.h2[q] = pk(a - (float)h.x, b - (float)h.y);
  }
}
__device__ __forceinline__ void loadfrag_hi(const float* W, int tile, int lane,
                                            float scale, Frag& hi) {
  Frag lo;
  loadfrag_hl(W, tile, lane, scale, hi, lo);
  (void)lo;
}

}  // namespace

extern "C" __global__ __launch_bounds__(128, 1) void rnn2_pipe4(
    const float* __restrict__ x,
    const float* __restrict__ w_ih0,
    const float* __restrict__ w_hh0,
    const float* __restrict__ b_ih0,
    const float* __restrict__ b_hh0,
    const float* __restrict__ w_ih1,
    const float* __restrict__ w_hh1,
    const float* __restrict__ b_ih1,
    const float* __restrict__ b_hh1,
    const float* __restrict__ w_out,
    const float* __restrict__ b_out,
    float* __restrict__ out) {
  const int tid = (int)threadIdx.x;
  const int role = tid >> 6;   // wave 0 = layer0 producer, wave 1 = layer1 consumer
  const int lane = tid & 63;
  const int g = lane >> 4;
  const int m = lane & 15;
  const int rg = (int)blockIdx.x * 16 + m;

  // h0 ring: [slot][batch col][j] f16, 8 slots.  Column granule swizzled by
  // (g + (m>>2))&3 so each 16-lane quarter-wave spreads over all banks (2-way max).
  __shared__ __align__(16) _Float16 hbuf[8][16][32];
  const int swz = 8 * ((g + (m >> 2)) & 3);

  // ---- role-specific persistent state ----
  Frag Wh[2], Wl[2];      // A: Whh0 hi/lo (scaled)
  Frag Bh1[2], Bi1[2];    // B: Whh1 hi, Wih1 hi (scaled)
  float cv[8];            // A: scaled c0 ; B: scaled c1   (slot i <-> j = 8g+i)
  float wih0v[8];         // A (scaled)
  float woutv[8];         // B (unscaled)
  float bout = 0.f;
  Frag h0, h1;
#pragma unroll
  for (int q = 0; q < 4; ++q) { h0.u[q] = 0; h1.u[q] = 0; }

  if (role == 0) {
#pragma unroll
    for (int t = 0; t < 2; ++t) loadfrag_hl(w_hh0, t, lane, kS, Wh[t], Wl[t]);
#pragma unroll
    for (int i = 0; i < 8; ++i) {
      int jj = 8 * g + i;
      cv[i] = (b_ih0[jj] + b_hh0[jj]) * kS;
      wih0v[i] = w_ih0[jj] * kS;
    }
  } else {
#pragma unroll
    for (int t = 0; t < 2; ++t) {
      loadfrag_hi(w_hh1, t, lane, kS, Bh1[t]);
      loadfrag_hi(w_ih1, t, lane, kS, Bi1[t]);
    }
#pragma unroll
    for (int i = 0; i < 8; ++i) {
      int jj = 8 * g + i;
      cv[i] = (b_ih1[jj] + b_hh1[jj]) * kS;
      woutv[i] = w_out[jj];
    }
    bout = b_out[0];
  }

  const float* xrow = x + (long)rg * kT;
  float* orow = out + (long)rg * kT;

  // ---- wave A: one layer-0 step; writes h0(t) into ring slot ----
  auto stepA = [&](float xt, int slot) {
    f32x4 z0 = {fmaf(xt, wih0v[0], cv[0]), fmaf(xt, wih0v[1], cv[1]),
                fmaf(xt, wih0v[2], cv[2]), fmaf(xt, wih0v[3], cv[3])};
    f32x4 z1 = {fmaf(xt, wih0v[4], cv[4]), fmaf(xt, wih0v[5], cv[5]),
                fmaf(xt, wih0v[6], cv[6]), fmaf(xt, wih0v[7], cv[7])};
    z0 = mfma(Wh[0].v, h0.v, z0);
    z0 = mfma(Wl[0].v, h0.v, z0);
    z1 = mfma(Wh[1].v, h0.v, z1);
    z1 = mfma(Wl[1].v, h0.v, z1);
    float f0 = tanh_ps(z0[0]), f1 = tanh_ps(z0[1]);
    float f2 = tanh_ps(z0[2]), f3 = tanh_ps(z0[3]);
    float f4 = tanh_ps(z1[0]), f5 = tanh_ps(z1[1]);
    float f6 = tanh_ps(z1[2]), f7 = tanh_ps(z1[3]);
    h0.h2[0] = pk(f0, f1); h0.h2[1] = pk(f2, f3);
    h0.h2[2] = pk(f4, f5); h0.h2[3] = pk(f6, f7);
    *reinterpret_cast<f16x8*>(&hbuf[slot][m][swz]) = h0.v;
  };

  float stash[16];
  // ---- wave B: one layer-1 step; stash per-lane output partial ----
  auto stepB = [&](const Frag& hf, float* st) {
    f32x4 y0 = {cv[0], cv[1], cv[2], cv[3]};
    f32x4 y1 = {cv[4], cv[5], cv[6], cv[7]};
    y0 = mfma(Bh1[0].v, h1.v, y0);
    y1 = mfma(Bh1[1].v, h1.v, y1);
    y0 = mfma(Bi1[0].v, hf.v, y0);
    y1 = mfma(Bi1[1].v, hf.v, y1);
    float f0 = tanh_ps(y0[0]), f1 = tanh_ps(y0[1]);
    float f2 = tanh_ps(y0[2]), f3 = tanh_ps(y0[3]);
    float f4 = tanh_ps(y1[0]), f5 = tanh_ps(y1[1]);
    float f6 = tanh_ps(y1[2]), f7 = tanh_ps(y1[3]);
    h1.h2[0] = pk(f0, f1); h1.h2[1] = pk(f2, f3);
    h1.h2[2] = pk(f4, f5); h1.h2[3] = pk(f6, f7);
    float oa = fmaf(woutv[0], f0, woutv[1] * f1);
    float ob = fmaf(woutv[2], f2, woutv[3] * f3);
    oa = fmaf(woutv[4], f4, oa);
    ob = fmaf(woutv[5], f5, ob);
    oa = fmaf(woutv[6], f6, oa);
    ob = fmaf(woutv[7], f7, ob);
    *st = oa + ob;   // cross-lane reduce deferred (batched per 16 steps)
  };

  auto readslot = [&](int slot) {
    Frag r;
    r.v = *reinterpret_cast<const f16x8*>(&hbuf[slot][m][swz]);
    return r;
  };

  auto reduce_store = [&](int base) {
    float r[16];
#pragma unroll
    for (int i = 0; i < 16; ++i) {
      float s = stash[i];
      s += __shfl_xor(s, 16, 64);
      s += __shfl_xor(s, 32, 64);
      r[i] = s + bout;
    }
    if (lane < 16) {
      float4* dst = (float4*)(orow + base);
      dst[0] = make_float4(r[0], r[1], r[2], r[3]);
      dst[1] = make_float4(r[4], r[5], r[6], r[7]);
      dst[2] = make_float4(r[8], r[9], r[10], r[11]);
      dst[3] = make_float4(r[12], r[13], r[14], r[15]);
    }
  };

  // x staging (A): current block xc, prefetched next block xn
  float xc[16], xn[16];
  if (role == 0) {
    float4 q0 = ((const float4*)xrow)[0], q1 = ((const float4*)xrow)[1];
    float4 q2 = ((const float4*)xrow)[2], q3 = ((const float4*)xrow)[3];
    xn[0]=q0.x; xn[1]=q0.y; xn[2]=q0.z; xn[3]=q0.w;
    xn[4]=q1.x; xn[5]=q1.y; xn[6]=q1.z; xn[7]=q1.w;
    xn[8]=q2.x; xn[9]=q2.y; xn[10]=q2.z; xn[11]=q2.w;
    xn[12]=q3.x; xn[13]=q3.y; xn[14]=q3.z; xn[15]=q3.w;
  }

  Frag pf[4];
#pragma unroll
  for (int k = 0; k < 4; ++k)
#pragma unroll
    for (int q = 0; q < 4; ++q) pf[k].u[q] = 0;

  // Phase p: A computes t = 4p..4p+3 (slots (4p+k)&7);
  //          B consumes s = 4(p-1)..4(p-1)+3 (disjoint slot half); barrier/phase.
  // Outer loop stride 4 keeps every ring/stash index compile-time constant.
  for (int p4 = 0; p4 < kPhases; p4 += 4) {
#pragma unroll
    for (int pp = 0; pp < 4; ++pp) {
      const int p = p4 + pp;
      if (role == 0) {
        if (pp == 0) {
#pragma unroll
          for (int i = 0; i < 16; ++i) xc[i] = xn[i];
          const int nb = ((p4 >> 2) + 1 < kNSB) ? ((p4 >> 2) + 1) : (kNSB - 1);
          const float* src = xrow + nb * 16;
          float4 q0 = ((const float4*)src)[0], q1 = ((const float4*)src)[1];
          float4 q2 = ((const float4*)src)[2], q3 = ((const float4*)src)[3];
          xn[0]=q0.x; xn[1]=q0.y; xn[2]=q0.z; xn[3]=q0.w;
          xn[4]=q1.x; xn[5]=q1.y; xn[6]=q1.z; xn[7]=q1.w;
          xn[8]=q2.x; xn[9]=q2.y; xn[10]=q2.z; xn[11]=q2.w;
          xn[12]=q3.x; xn[13]=q3.y; xn[14]=q3.z; xn[15]=q3.w;
        }
        stepA(xc[4 * pp + 0], (4 * pp + 0) & 7);
        stepA(xc[4 * pp + 1], (4 * pp + 1) & 7);
        stepA(xc[4 * pp + 2], (4 * pp + 2) & 7);
        stepA(xc[4 * pp + 3], (4 * pp + 3) & 7);
      } else {
        if (pp == 1 && p4 >= 4) reduce_store(((p4 - 4) >> 2) * 16);
        if (p >= 1) {
          pf[0] = readslot((4 * pp + 4) & 7);
          pf[1] = readslot((4 * pp + 5) & 7);
          pf[2] = readslot((4 * pp + 6) & 7);
          pf[3] = readslot((4 * pp + 7) & 7);
          stepB(pf[0], &stash[(4 * pp + 12) & 15]);
          stepB(pf[1], &stash[(4 * pp + 13) & 15]);
          stepB(pf[2], &stash[(4 * pp + 14) & 15]);
          stepB(pf[3], &stash[(4 * pp + 15) & 15]);
        }
      }
      // lgkm-only barrier: orders LDS ring across waves without draining
      // A's global x-prefetch (vmcnt) every phase.
      asm volatile("s_waitcnt lgkmcnt(0)\n\ts_barrier" ::: "memory");
    }
  }

  // Epilogue: B drains s = 2044..2047 (slots 4..7) and stores block 127.
  if (role == 1) {
    pf[0] = readslot(4); pf[1] = readslot(5);
    pf[2] = readslot(6); pf[3] = readslot(7);
    stepB(pf[0], &stash[12]);
    stepB(pf[1], &stash[13]);
    stepB(pf[2], &stash[14]);
    stepB(pf[3], &stash[15]);
    reduce_store(kT - 16);
  }
}

extern "C" void kernel_launch(void* const* d_in, const int* in_sizes, int n_in,
                              void* d_out, int out_size, void* d_ws, size_t ws_size,
                              hipStream_t stream) {
  (void)in_sizes; (void)n_in; (void)d_ws; (void)ws_size; (void)out_size;
  const float* xp = (const float*)d_in[0];
  const float* w_ih0 = (const float*)d_in[1];
  const float* w_hh0 = (const float*)d_in[2];
  const float* b_ih0 = (const float*)d_in[3];
  const float* b_hh0 = (const float*)d_in[4];
  const float* w_ih1 = (const float*)d_in[5];
  const float* w_hh1 = (const float*)d_in[6];
  const float* b_ih1 = (const float*)d_in[7];
  const float* b_hh1 = (const float*)d_in[8];
  const float* w_out = (const float*)d_in[9];
  const float* b_out = (const float*)d_in[10];
  // d_in[11] = future (0 in this harness)

  dim3 grid(kB / 16);   // 256 blocks, one 16-row batch tile each
  dim3 block(128);      // 2 waves: layer0 producer + layer1 consumer
  hipLaunchKernelGGL(rnn2_pipe4, grid, block, 0, stream,
                     xp, w_ih0, w_hh0, b_ih0, b_hh0,
                     w_ih1, w_hh1, b_ih1, b_hh1,
                     w_out, b_out, (float*)d_out);
}